// Round 3
// baseline (284.527 us; speedup 1.0000x reference)
//
#include <hip/hip_runtime.h>
#include <stdint.h>

#define S_LEN 2048
#define BATCH 2
#define DM 1024
#define NH 16
#define DH 64
#define MROWS 4096  // BATCH * S_LEN

typedef unsigned short u16;
typedef unsigned int u32;
typedef __attribute__((ext_vector_type(8))) short bf16x8;
typedef __attribute__((ext_vector_type(4))) short bf16x4;
typedef __attribute__((ext_vector_type(4))) float f32x4;
typedef __attribute__((ext_vector_type(2))) unsigned u32x2;

union pack8 { bf16x4 h[2]; u32 w[4]; bf16x8 v8; };

__device__ inline u16 f2bf(float f) {
  union { float f; unsigned u; } v; v.f = f;
  unsigned u = v.u;
  unsigned r = u + 0x7fffu + ((u >> 16) & 1u);
  return (u16)(r >> 16);
}

__device__ inline u32 pkbf(float lo, float hi) {
  u32 r;
  asm("v_cvt_pk_bf16_f32 %0, %1, %2" : "=v"(r) : "v"(lo), "v"(hi));
  return r;
}

// ---------------- fp32 -> bf16 conversion for x, Wq, Wk, Wv, Wo ----------------
__global__ void convert_k(const float* __restrict__ x, const float* __restrict__ wq,
                          const float* __restrict__ wk, const float* __restrict__ wv,
                          const float* __restrict__ wo, u16* __restrict__ xb,
                          u16* __restrict__ wb) {
  int i = blockIdx.x * blockDim.x + threadIdx.x;
  const int total = (MROWS * DM + 4 * DM * DM) / 4;  // 2,097,152 float4 groups
  if (i >= total) return;
  int e = i * 4;
  const float* src;
  u16* dst;
  if (e < MROWS * DM) {
    src = x + e; dst = xb + e;
  } else {
    int j = e - MROWS * DM;
    int w = j >> 20;
    int o = j & ((1 << 20) - 1);
    src = (w == 0) ? wq + o : (w == 1) ? wk + o : (w == 2) ? wv + o : wo + o;
    dst = wb + j;
  }
  float4 v = *(const float4*)src;
  uint2 r;
  r.x = (unsigned)f2bf(v.x) | ((unsigned)f2bf(v.y) << 16);
  r.y = (unsigned)f2bf(v.z) | ((unsigned)f2bf(v.w) << 16);
  *(uint2*)dst = r;
}

// ---------------- RoPE cos/sin table [S][32] ----------------
__global__ void rope_k(float2* __restrict__ tab) {
  int i = blockIdx.x * blockDim.x + threadIdx.x;
  if (i >= S_LEN * 32) return;
  int s = i >> 5, p = i & 31;
  float inv = expf(-(float)p * 0.28782313662425575f);  // ln(10000)/32
  float a = (float)s * inv;
  tab[i] = make_float2(cosf(a), sinf(a));
}

// ---------------- GEMM: C = A @ W^T + bias, fused epilogues ----------------
// mode 0: Q  -> rope, *0.125*log2e, bf16 [B,H,S,Dh]   (log2e folded so attn uses exp2)
// mode 1: K  -> rope, bf16 [B,H,S,Dh]
// mode 2: V  -> bf16 transposed [B,H,Dh,S]
// mode 3: O  -> fp32 [M, DM]
__launch_bounds__(256)
__global__ void gemm_k(const u16* __restrict__ A,
                       const u16* __restrict__ w0, const u16* __restrict__ w1,
                       const u16* __restrict__ w2,
                       const float* __restrict__ b0, const float* __restrict__ b1,
                       const float* __restrict__ b2,
                       const float2* __restrict__ rope,
                       void* __restrict__ o0, void* __restrict__ o1, void* __restrict__ o2,
                       int mode0) {
  const int mode = mode0 + (int)(blockIdx.x >> 8);
  const int tile = blockIdx.x & 255;
  const int mt = tile >> 3, nt = tile & 7;
  const int mbase = mt * 128, nbase = nt * 128;
  const u16* W = (mode == 1) ? w1 : (mode == 2) ? w2 : w0;
  const float* bias = (mode == 1) ? b1 : (mode == 2) ? b2 : b0;
  void* outp = (mode == 1) ? o1 : (mode == 2) ? o2 : o0;

  __shared__ u16 As[128 * 40];  // padded row stride 40 (2-way bank aliasing = free)
  __shared__ u16 Bs[128 * 40];

  const int t = threadIdx.x;
  const int lane = t & 63, wvi = t >> 6;
  const int lr = lane & 15, lg = lane >> 4;
  const int wm = (wvi >> 1) * 64, wn = (wvi & 1) * 64;

  f32x4 acc[4][4] = {};
  const int srow = t >> 2;        // 0..63
  const int scol = (t & 3) * 8;   // 0,8,16,24

  for (int kk = 0; kk < DM; kk += 32) {
    bf16x8 a0 = *(const bf16x8*)(A + (size_t)(mbase + srow) * DM + kk + scol);
    bf16x8 a1 = *(const bf16x8*)(A + (size_t)(mbase + 64 + srow) * DM + kk + scol);
    bf16x8 g0 = *(const bf16x8*)(W + (size_t)(nbase + srow) * DM + kk + scol);
    bf16x8 g1 = *(const bf16x8*)(W + (size_t)(nbase + 64 + srow) * DM + kk + scol);
    __syncthreads();
    *(bf16x8*)&As[srow * 40 + scol] = a0;
    *(bf16x8*)&As[(64 + srow) * 40 + scol] = a1;
    *(bf16x8*)&Bs[srow * 40 + scol] = g0;
    *(bf16x8*)&Bs[(64 + srow) * 40 + scol] = g1;
    __syncthreads();
    bf16x8 af[4], bfr[4];
#pragma unroll
    for (int mi = 0; mi < 4; mi++)
      af[mi] = *(const bf16x8*)&As[(wm + mi * 16 + lr) * 40 + lg * 8];
#pragma unroll
    for (int ni = 0; ni < 4; ni++)
      bfr[ni] = *(const bf16x8*)&Bs[(wn + ni * 16 + lr) * 40 + lg * 8];
#pragma unroll
    for (int mi = 0; mi < 4; mi++)
#pragma unroll
      for (int ni = 0; ni < 4; ni++)
        acc[mi][ni] = __builtin_amdgcn_mfma_f32_16x16x32_bf16(af[mi], bfr[ni], acc[mi][ni], 0, 0, 0);
  }

#pragma unroll
  for (int ni = 0; ni < 4; ni++) {
    const int col = nbase + wn + ni * 16 + lr;
    const float bv = bias[col];
#pragma unroll
    for (int mi = 0; mi < 4; mi++) {
      const int row0 = mbase + wm + mi * 16 + lg * 4;
      f32x4 v = acc[mi][ni];
#pragma unroll
      for (int r = 0; r < 4; r++) {
        float val = v[r] + bv;
        const int row = row0 + r;
        if (mode <= 1) {
          float nb = __shfl_xor(val, 1);
          const int d = col & 63, p = d >> 1, s = row & (S_LEN - 1);
          float2 cs = rope[s * 32 + p];
          float ov = (d & 1) ? (nb * cs.y + val * cs.x) : (val * cs.x - nb * cs.y);
          if (mode == 0) ov *= 0.18033688011112042f;  // 1/sqrt(Dh) * log2(e)
          const int b = row >> 11, h = col >> 6;
          ((u16*)outp)[((size_t)(b * NH + h) * S_LEN + s) * DH + d] = f2bf(ov);
        } else if (mode == 2) {
          const int b = row >> 11, h = col >> 6, d = col & 63, s = row & (S_LEN - 1);
          ((u16*)outp)[((size_t)(b * NH + h) * DH + d) * S_LEN + s] = f2bf(val);
        } else {
          ((float*)outp)[(size_t)row * DM + col] = val;
        }
      }
    }
  }
}

// ---------------- causal flash attention, all-register P ----------------
// S^T = mfma(K, Q): lane(lr,lg) holds S^T[kv = lg*4+r (+16)][q = lr].
// P stays in registers: PV uses a custom-but-consistent k-bijection
// sigma(lg,e) = lg*4+e (e<4) / 16+lg*4+(e-4) (e>=4) for BOTH the Vt A-frag
// (two 8B loads per dt) and the P B-frag (pkbf-packed). No LDS, no barriers,
// K double-buffered, V issued early -> compiler can pipeline across steps.
// Defer-max (THR=8 in log2 domain); l reduced cross-lane only at epilogue.
__launch_bounds__(128)
__global__ void attn_k(const u16* __restrict__ Q, const u16* __restrict__ K,
                       const u16* __restrict__ Vt, u16* __restrict__ Oo) {
  const int bh = blockIdx.x & 31;
  const int pr = blockIdx.x >> 5;           // 0..63
  const int wv = threadIdx.x >> 6;          // wave 0/1
  const int lane = threadIdx.x & 63;
  const int lr = lane & 15, lg = lane >> 4;
  const int tile = 127 - (pr * 2 + wv);     // longest first (causal load balance)
  const int qbase = tile * 16;

  const size_t qoff = ((size_t)bh * S_LEN + qbase + lr) * DH + lg * 8;
  const bf16x8 q0 = *(const bf16x8*)(Q + qoff);
  const bf16x8 q1 = *(const bf16x8*)(Q + qoff + 32);

  f32x4 o[4] = {};
  float m = -__builtin_inff(), l = 0.f;
  const f32x4 zero = {};
  const int nsteps = (qbase + 47) >> 5;

  // K double-buffer: preload step 0
  const u16* Kp = K + ((size_t)bh * S_LEN + lr) * DH + lg * 8;
  bf16x8 kc0 = *(const bf16x8*)(Kp);
  bf16x8 kc1 = *(const bf16x8*)(Kp + 32);
  bf16x8 kc2 = *(const bf16x8*)(Kp + 16 * DH);
  bf16x8 kc3 = *(const bf16x8*)(Kp + 16 * DH + 32);
  const u16* Vp = Vt + ((size_t)bh * DH + lr) * S_LEN + lg * 4;

  for (int step = 0; step < nsteps; ++step) {
    const int kv = step << 5;
    // ---- V for current step, issued early (consumed only after softmax) ----
    bf16x4 v[8];
#pragma unroll
    for (int dt = 0; dt < 4; dt++) {
      v[2 * dt]     = *(const bf16x4*)(Vp + dt * 16 * S_LEN);
      v[2 * dt + 1] = *(const bf16x4*)(Vp + dt * 16 * S_LEN + 16);
    }
    Vp += 32;

    // ---- QK^T (swapped): A = K rows, B = Q rows ----
    f32x4 s0 = __builtin_amdgcn_mfma_f32_16x16x32_bf16(kc0, q0, zero, 0, 0, 0);
    s0 = __builtin_amdgcn_mfma_f32_16x16x32_bf16(kc1, q1, s0, 0, 0, 0);
    f32x4 s1 = __builtin_amdgcn_mfma_f32_16x16x32_bf16(kc2, q0, zero, 0, 0, 0);
    s1 = __builtin_amdgcn_mfma_f32_16x16x32_bf16(kc3, q1, s1, 0, 0, 0);

    // ---- prefetch next step's K (harmless overread past last tile) ----
    Kp += 32 * DH;
    kc0 = *(const bf16x8*)(Kp);
    kc1 = *(const bf16x8*)(Kp + 32);
    kc2 = *(const bf16x8*)(Kp + 16 * DH);
    kc3 = *(const bf16x8*)(Kp + 16 * DH + 32);

    // ---- causal mask (only the last step straddles the diagonal) ----
    float a[8];
    if (step == nsteps - 1) {
      const int qrel = qbase + lr - kv - lg * 4;  // valid: (kv + lg*4 + r) <= q
#pragma unroll
      for (int r = 0; r < 4; r++) {
        a[r]     = (r <= qrel)      ? s0[r] : -__builtin_inff();
        a[4 + r] = (r + 16 <= qrel) ? s1[r] : -__builtin_inff();
      }
    } else {
#pragma unroll
      for (int r = 0; r < 4; r++) { a[r] = s0[r]; a[4 + r] = s1[r]; }
    }

    // ---- column max over 32 kv: in-lane tree + 2 shfl ----
    float mx = fmaxf(fmaxf(fmaxf(a[0], a[1]), fmaxf(a[2], a[3])),
                     fmaxf(fmaxf(a[4], a[5]), fmaxf(a[6], a[7])));
    mx = fmaxf(mx, __shfl_xor(mx, 16));
    mx = fmaxf(mx, __shfl_xor(mx, 32));

    // ---- defer-max: rescale only when some column grew past THR=8 ----
    if (!__all(mx - m <= 8.0f)) {
      const float mn = fmaxf(m, mx);
      const float corr = __builtin_amdgcn_exp2f(m - mn);  // step 0: exp2(-inf)=0
      m = mn;
      l *= corr;
#pragma unroll
      for (int dt = 0; dt < 4; dt++)
#pragma unroll
        for (int r = 0; r < 4; r++) o[dt][r] *= corr;
    }

    float p[8];
#pragma unroll
    for (int r = 0; r < 8; r++) p[r] = __builtin_amdgcn_exp2f(a[r] - m);
    l += ((p[0] + p[1]) + (p[2] + p[3])) + ((p[4] + p[5]) + (p[6] + p[7]));

    // ---- P -> bf16 B-frag in registers (bijection sigma) ----
    pack8 pu;
    pu.w[0] = pkbf(p[0], p[1]);
    pu.w[1] = pkbf(p[2], p[3]);
    pu.w[2] = pkbf(p[4], p[5]);
    pu.w[3] = pkbf(p[6], p[7]);

    // ---- PV: O^T += Vt-frag (same sigma) x P ----
#pragma unroll
    for (int dt = 0; dt < 4; dt++) {
      pack8 vf;
      vf.h[0] = v[2 * dt];
      vf.h[1] = v[2 * dt + 1];
      o[dt] = __builtin_amdgcn_mfma_f32_16x16x32_bf16(vf.v8, pu.v8, o[dt], 0, 0, 0);
    }
  }

  // ---- epilogue: lane holds q=lr, d = dt*16 + lg*4 + r ----
  l += __shfl_xor(l, 16);
  l += __shfl_xor(l, 32);
  const int b = bh >> 4, h = bh & 15;
  const float rl = __builtin_amdgcn_rcpf(l);
  const size_t obase = ((size_t)b * S_LEN + qbase + lr) * DM + h * DH;
#pragma unroll
  for (int dt = 0; dt < 4; dt++) {
    u32x2 pk;
    pk.x = pkbf(o[dt][0] * rl, o[dt][1] * rl);
    pk.y = pkbf(o[dt][2] * rl, o[dt][3] * rl);
    *(u32x2*)(Oo + obase + dt * 16 + lg * 4) = pk;
  }
}

// ---------------- host launcher ----------------
extern "C" void kernel_launch(void* const* d_in, const int* in_sizes, int n_in,
                              void* d_out, int out_size, void* d_ws, size_t ws_size,
                              hipStream_t stream) {
  const float* x  = (const float*)d_in[0];
  const float* Wq = (const float*)d_in[1];
  const float* bq = (const float*)d_in[2];
  const float* Wk = (const float*)d_in[3];
  const float* bk = (const float*)d_in[4];
  const float* Wv = (const float*)d_in[5];
  const float* bv = (const float*)d_in[6];
  const float* Wo = (const float*)d_in[7];
  const float* bo = (const float*)d_in[8];

  char* ws = (char*)d_ws;
  u16* xb    = (u16*)(ws);                 // 8 MB  [4096,1024] bf16
  u16* wb    = (u16*)(ws + (8u << 20));    // 8 MB  Wq,Wk,Wv,Wo bf16
  u16* Qb    = (u16*)(ws + (16u << 20));   // 8 MB  [B,H,S,Dh]
  u16* Kb    = (u16*)(ws + (24u << 20));   // 8 MB  [B,H,S,Dh]
  u16* Vtb   = (u16*)(ws + (32u << 20));   // 8 MB  [B,H,Dh,S]
  u16* AOb   = (u16*)(ws + (40u << 20));   // 8 MB  [B*S, DM]
  float2* rt = (float2*)(ws + (48u << 20)); // 512 KB rope table

  convert_k<<<8192, 256, 0, stream>>>(x, Wq, Wk, Wv, Wo, xb, wb);
  rope_k<<<256, 256, 0, stream>>>(rt);
  gemm_k<<<768, 256, 0, stream>>>(xb, wb, wb + (1u << 20), wb + (2u << 20),
                                  bq, bk, bv, rt, Qb, Kb, Vtb, 0);
  attn_k<<<2048, 128, 0, stream>>>(Qb, Kb, Vtb, AOb);
  gemm_k<<<256, 256, 0, stream>>>(AOb, wb + (3u << 20), wb + (3u << 20), wb + (3u << 20),
                                  bo, bo, bo, rt, d_out, d_out, d_out, 3);
}

// Round 4
// 222.749 us; speedup vs baseline: 1.2773x; 1.2773x over previous
//
#include <hip/hip_runtime.h>
#include <stdint.h>

#define S_LEN 2048
#define BATCH 2
#define DM 1024
#define NH 16
#define DH 64
#define MROWS 4096  // BATCH * S_LEN

typedef unsigned short u16;
typedef unsigned int u32;
typedef __attribute__((ext_vector_type(8))) short bf16x8;
typedef __attribute__((ext_vector_type(4))) short bf16x4;
typedef __attribute__((ext_vector_type(4))) float f32x4;
typedef __attribute__((ext_vector_type(2))) unsigned u32x2;

union pack8 { u32 w[4]; bf16x8 v8; };

__device__ inline u16 f2bf(float f) {
  union { float f; unsigned u; } v; v.f = f;
  unsigned u = v.u;
  unsigned r = u + 0x7fffu + ((u >> 16) & 1u);
  return (u16)(r >> 16);
}

__device__ inline u32 pkbf(float lo, float hi) {
  u32 r;
  asm("v_cvt_pk_bf16_f32 %0, %1, %2" : "=v"(r) : "v"(lo), "v"(hi));
  return r;
}

// ---------------- fp32 -> bf16 conversion for x, Wq, Wk, Wv, Wo ----------------
__global__ void convert_k(const float* __restrict__ x, const float* __restrict__ wq,
                          const float* __restrict__ wk, const float* __restrict__ wv,
                          const float* __restrict__ wo, u16* __restrict__ xb,
                          u16* __restrict__ wb) {
  int i = blockIdx.x * blockDim.x + threadIdx.x;
  const int total = (MROWS * DM + 4 * DM * DM) / 4;  // 2,097,152 float4 groups
  if (i >= total) return;
  int e = i * 4;
  const float* src;
  u16* dst;
  if (e < MROWS * DM) {
    src = x + e; dst = xb + e;
  } else {
    int j = e - MROWS * DM;
    int w = j >> 20;
    int o = j & ((1 << 20) - 1);
    src = (w == 0) ? wq + o : (w == 1) ? wk + o : (w == 2) ? wv + o : wo + o;
    dst = wb + j;
  }
  float4 v = *(const float4*)src;
  uint2 r;
  r.x = (unsigned)f2bf(v.x) | ((unsigned)f2bf(v.y) << 16);
  r.y = (unsigned)f2bf(v.z) | ((unsigned)f2bf(v.w) << 16);
  *(uint2*)dst = r;
}

// ---------------- RoPE cos/sin table [S][32] ----------------
__global__ void rope_k(float2* __restrict__ tab) {
  int i = blockIdx.x * blockDim.x + threadIdx.x;
  if (i >= S_LEN * 32) return;
  int s = i >> 5, p = i & 31;
  float inv = expf(-(float)p * 0.28782313662425575f);  // ln(10000)/32
  float a = (float)s * inv;
  tab[i] = make_float2(cosf(a), sinf(a));
}

// ---------------- GEMM: C = A @ W^T + bias, fused epilogues ----------------
// mode 0: Q  -> rope, *0.125*log2e, bf16 [B,H,S,Dh]   (log2e folded so attn uses exp2)
// mode 1: K  -> rope, bf16 [B,H,S,Dh]
// mode 2: V  -> bf16 [B,H,Dh,S] with per-32 s-block permutation matching the
//               attn PV fragment (pos = ((j&15)>>2)*8 + (j>>4)*4 + (j&3))
// mode 3: O  -> fp32 [M, DM]
__launch_bounds__(256)
__global__ void gemm_k(const u16* __restrict__ A,
                       const u16* __restrict__ w0, const u16* __restrict__ w1,
                       const u16* __restrict__ w2,
                       const float* __restrict__ b0, const float* __restrict__ b1,
                       const float* __restrict__ b2,
                       const float2* __restrict__ rope,
                       void* __restrict__ o0, void* __restrict__ o1, void* __restrict__ o2,
                       int mode0) {
  const int mode = mode0 + (int)(blockIdx.x >> 8);
  const int tile = blockIdx.x & 255;
  const int mt = tile >> 3, nt = tile & 7;
  const int mbase = mt * 128, nbase = nt * 128;
  const u16* W = (mode == 1) ? w1 : (mode == 2) ? w2 : w0;
  const float* bias = (mode == 1) ? b1 : (mode == 2) ? b2 : b0;
  void* outp = (mode == 1) ? o1 : (mode == 2) ? o2 : o0;

  __shared__ u16 As[128 * 40];  // padded row stride 40 (2-way bank aliasing = free)
  __shared__ u16 Bs[128 * 40];

  const int t = threadIdx.x;
  const int lane = t & 63, wvi = t >> 6;
  const int lr = lane & 15, lg = lane >> 4;
  const int wm = (wvi >> 1) * 64, wn = (wvi & 1) * 64;

  f32x4 acc[4][4] = {};
  const int srow = t >> 2;        // 0..63
  const int scol = (t & 3) * 8;   // 0,8,16,24

  for (int kk = 0; kk < DM; kk += 32) {
    bf16x8 a0 = *(const bf16x8*)(A + (size_t)(mbase + srow) * DM + kk + scol);
    bf16x8 a1 = *(const bf16x8*)(A + (size_t)(mbase + 64 + srow) * DM + kk + scol);
    bf16x8 g0 = *(const bf16x8*)(W + (size_t)(nbase + srow) * DM + kk + scol);
    bf16x8 g1 = *(const bf16x8*)(W + (size_t)(nbase + 64 + srow) * DM + kk + scol);
    __syncthreads();
    *(bf16x8*)&As[srow * 40 + scol] = a0;
    *(bf16x8*)&As[(64 + srow) * 40 + scol] = a1;
    *(bf16x8*)&Bs[srow * 40 + scol] = g0;
    *(bf16x8*)&Bs[(64 + srow) * 40 + scol] = g1;
    __syncthreads();
    bf16x8 af[4], bfr[4];
#pragma unroll
    for (int mi = 0; mi < 4; mi++)
      af[mi] = *(const bf16x8*)&As[(wm + mi * 16 + lr) * 40 + lg * 8];
#pragma unroll
    for (int ni = 0; ni < 4; ni++)
      bfr[ni] = *(const bf16x8*)&Bs[(wn + ni * 16 + lr) * 40 + lg * 8];
#pragma unroll
    for (int mi = 0; mi < 4; mi++)
#pragma unroll
      for (int ni = 0; ni < 4; ni++)
        acc[mi][ni] = __builtin_amdgcn_mfma_f32_16x16x32_bf16(af[mi], bfr[ni], acc[mi][ni], 0, 0, 0);
  }

#pragma unroll
  for (int ni = 0; ni < 4; ni++) {
    const int col = nbase + wn + ni * 16 + lr;
    const float bv = bias[col];
#pragma unroll
    for (int mi = 0; mi < 4; mi++) {
      const int row0 = mbase + wm + mi * 16 + lg * 4;
      f32x4 v = acc[mi][ni];
#pragma unroll
      for (int r = 0; r < 4; r++) {
        float val = v[r] + bv;
        const int row = row0 + r;
        if (mode <= 1) {
          float nb = __shfl_xor(val, 1);
          const int d = col & 63, p = d >> 1, s = row & (S_LEN - 1);
          float2 cs = rope[s * 32 + p];
          float ov = (d & 1) ? (nb * cs.y + val * cs.x) : (val * cs.x - nb * cs.y);
          if (mode == 0) ov *= 0.18033688011112042f;  // 1/sqrt(Dh) * log2(e)
          const int b = row >> 11, h = col >> 6;
          ((u16*)outp)[((size_t)(b * NH + h) * S_LEN + s) * DH + d] = f2bf(ov);
        } else if (mode == 2) {
          const int b = row >> 11, h = col >> 6, d = col & 63, s = row & (S_LEN - 1);
          const int j = s & 31;
          const int pos = (s & ~31) + (((j & 15) >> 2) << 3) + ((j >> 4) << 2) + (j & 3);
          ((u16*)outp)[((size_t)(b * NH + h) * DH + d) * S_LEN + pos] = f2bf(val);
        } else {
          ((float*)outp)[(size_t)row * DM + col] = val;
        }
      }
    }
  }
}

// ---------------- causal flash attention, all-register P, branch-free body ----
// S^T = mfma(K, Q): lane(lr,lg) holds S^T[kv = lg*4+r (+16)][q = lr].
// P stays in registers via bijection sigma(lg,e) = {lg*4+e, 16+lg*4+(e-4)};
// Vt is PRE-PERMUTED (gemm mode 2) so the matching V A-frag is one 16B load.
// Hot loop body is a single basic block (masked last step peeled) so the
// backend can pipeline loads/MFMAs across the softmax chain.
__launch_bounds__(128)
__global__ void attn_k(const u16* __restrict__ Q, const u16* __restrict__ K,
                       const u16* __restrict__ Vt, u16* __restrict__ Oo) {
  const int bh = blockIdx.x & 31;
  const int pr = blockIdx.x >> 5;           // 0..63
  const int wv = threadIdx.x >> 6;          // wave 0/1
  const int lane = threadIdx.x & 63;
  const int lr = lane & 15, lg = lane >> 4;
  const int tile = 127 - (pr * 2 + wv);     // longest first (causal load balance)
  const int qbase = tile * 16;

  const size_t qoff = ((size_t)bh * S_LEN + qbase + lr) * DH + lg * 8;
  const bf16x8 q0 = *(const bf16x8*)(Q + qoff);
  const bf16x8 q1 = *(const bf16x8*)(Q + qoff + 32);

  f32x4 o[4] = {};
  float m = -__builtin_inff(), l = 0.f;
  const f32x4 zero = {};
  const int nsteps = (qbase + 47) >> 5;

  // K register double-buffer: preload step 0
  const u16* Kp = K + ((size_t)bh * S_LEN + lr) * DH + lg * 8;
  bf16x8 kc0 = *(const bf16x8*)(Kp);
  bf16x8 kc1 = *(const bf16x8*)(Kp + 32);
  bf16x8 kc2 = *(const bf16x8*)(Kp + 16 * DH);
  bf16x8 kc3 = *(const bf16x8*)(Kp + 16 * DH + 32);
  const u16* Vp = Vt + ((size_t)bh * DH + lr) * S_LEN + lg * 8;

  // ---- hot loop: steps 0 .. nsteps-2, zero branches in body ----
  for (int step = 0; step < nsteps - 1; ++step) {
    // V for current step (pre-permuted layout -> one dwordx4 per dt)
    bf16x8 v0 = *(const bf16x8*)(Vp);
    bf16x8 v1 = *(const bf16x8*)(Vp + 16 * S_LEN);
    bf16x8 v2 = *(const bf16x8*)(Vp + 32 * S_LEN);
    bf16x8 v3 = *(const bf16x8*)(Vp + 48 * S_LEN);
    Vp += 32;

    // QK^T (swapped): A = K rows, B = Q rows
    f32x4 s0 = __builtin_amdgcn_mfma_f32_16x16x32_bf16(kc0, q0, zero, 0, 0, 0);
    s0 = __builtin_amdgcn_mfma_f32_16x16x32_bf16(kc1, q1, s0, 0, 0, 0);
    f32x4 s1 = __builtin_amdgcn_mfma_f32_16x16x32_bf16(kc2, q0, zero, 0, 0, 0);
    s1 = __builtin_amdgcn_mfma_f32_16x16x32_bf16(kc3, q1, s1, 0, 0, 0);

    // prefetch next step's K (always exists: peeled step consumes the last one)
    Kp += 32 * DH;
    kc0 = *(const bf16x8*)(Kp);
    kc1 = *(const bf16x8*)(Kp + 32);
    kc2 = *(const bf16x8*)(Kp + 16 * DH);
    kc3 = *(const bf16x8*)(Kp + 16 * DH + 32);

    // branch-free online softmax over 32 kv
    float mx = fmaxf(fmaxf(fmaxf(s0[0], s0[1]), fmaxf(s0[2], s0[3])),
                     fmaxf(fmaxf(s1[0], s1[1]), fmaxf(s1[2], s1[3])));
    mx = fmaxf(mx, __shfl_xor(mx, 16));
    mx = fmaxf(mx, __shfl_xor(mx, 32));
    const float mn = fmaxf(m, mx);
    const float corr = __builtin_amdgcn_exp2f(m - mn);  // step 0: exp2(-inf)=0
    m = mn;

    float p[8];
#pragma unroll
    for (int r = 0; r < 4; r++) p[r] = __builtin_amdgcn_exp2f(s0[r] - mn);
#pragma unroll
    for (int r = 0; r < 4; r++) p[4 + r] = __builtin_amdgcn_exp2f(s1[r] - mn);
    l = l * corr + (((p[0] + p[1]) + (p[2] + p[3])) + ((p[4] + p[5]) + (p[6] + p[7])));

    pack8 pu;
    pu.w[0] = pkbf(p[0], p[1]);
    pu.w[1] = pkbf(p[2], p[3]);
    pu.w[2] = pkbf(p[4], p[5]);
    pu.w[3] = pkbf(p[6], p[7]);

#pragma unroll
    for (int dt = 0; dt < 4; dt++)
#pragma unroll
      for (int r = 0; r < 4; r++) o[dt][r] *= corr;

    o[0] = __builtin_amdgcn_mfma_f32_16x16x32_bf16(v0, pu.v8, o[0], 0, 0, 0);
    o[1] = __builtin_amdgcn_mfma_f32_16x16x32_bf16(v1, pu.v8, o[1], 0, 0, 0);
    o[2] = __builtin_amdgcn_mfma_f32_16x16x32_bf16(v2, pu.v8, o[2], 0, 0, 0);
    o[3] = __builtin_amdgcn_mfma_f32_16x16x32_bf16(v3, pu.v8, o[3], 0, 0, 0);
  }

  // ---- peeled masked last step (kv = (nsteps-1)*32) ----
  {
    const int kv = (nsteps - 1) << 5;
    bf16x8 v0 = *(const bf16x8*)(Vp);
    bf16x8 v1 = *(const bf16x8*)(Vp + 16 * S_LEN);
    bf16x8 v2 = *(const bf16x8*)(Vp + 32 * S_LEN);
    bf16x8 v3 = *(const bf16x8*)(Vp + 48 * S_LEN);

    f32x4 s0 = __builtin_amdgcn_mfma_f32_16x16x32_bf16(kc0, q0, zero, 0, 0, 0);
    s0 = __builtin_amdgcn_mfma_f32_16x16x32_bf16(kc1, q1, s0, 0, 0, 0);
    f32x4 s1 = __builtin_amdgcn_mfma_f32_16x16x32_bf16(kc2, q0, zero, 0, 0, 0);
    s1 = __builtin_amdgcn_mfma_f32_16x16x32_bf16(kc3, q1, s1, 0, 0, 0);

    const int qrel = qbase + lr - kv - lg * 4;  // valid: (kv + lg*4 + r) <= q
    float a[8];
#pragma unroll
    for (int r = 0; r < 4; r++) {
      a[r]     = (r <= qrel)      ? s0[r] : -__builtin_inff();
      a[4 + r] = (r + 16 <= qrel) ? s1[r] : -__builtin_inff();
    }
    float mx = fmaxf(fmaxf(fmaxf(a[0], a[1]), fmaxf(a[2], a[3])),
                     fmaxf(fmaxf(a[4], a[5]), fmaxf(a[6], a[7])));
    mx = fmaxf(mx, __shfl_xor(mx, 16));
    mx = fmaxf(mx, __shfl_xor(mx, 32));
    const float mn = fmaxf(m, mx);
    const float corr = __builtin_amdgcn_exp2f(m - mn);
    m = mn;

    float p[8];
#pragma unroll
    for (int r = 0; r < 8; r++) p[r] = __builtin_amdgcn_exp2f(a[r] - mn);
    l = l * corr + (((p[0] + p[1]) + (p[2] + p[3])) + ((p[4] + p[5]) + (p[6] + p[7])));

    pack8 pu;
    pu.w[0] = pkbf(p[0], p[1]);
    pu.w[1] = pkbf(p[2], p[3]);
    pu.w[2] = pkbf(p[4], p[5]);
    pu.w[3] = pkbf(p[6], p[7]);

#pragma unroll
    for (int dt = 0; dt < 4; dt++)
#pragma unroll
      for (int r = 0; r < 4; r++) o[dt][r] *= corr;

    o[0] = __builtin_amdgcn_mfma_f32_16x16x32_bf16(v0, pu.v8, o[0], 0, 0, 0);
    o[1] = __builtin_amdgcn_mfma_f32_16x16x32_bf16(v1, pu.v8, o[1], 0, 0, 0);
    o[2] = __builtin_amdgcn_mfma_f32_16x16x32_bf16(v2, pu.v8, o[2], 0, 0, 0);
    o[3] = __builtin_amdgcn_mfma_f32_16x16x32_bf16(v3, pu.v8, o[3], 0, 0, 0);
  }

  // ---- epilogue: lane holds q=lr, d = dt*16 + lg*4 + r ----
  l += __shfl_xor(l, 16);
  l += __shfl_xor(l, 32);
  const int b = bh >> 4, h = bh & 15;
  const float rl = __builtin_amdgcn_rcpf(l);
  const size_t obase = ((size_t)b * S_LEN + qbase + lr) * DM + h * DH;
#pragma unroll
  for (int dt = 0; dt < 4; dt++) {
    u32x2 pk;
    pk.x = pkbf(o[dt][0] * rl, o[dt][1] * rl);
    pk.y = pkbf(o[dt][2] * rl, o[dt][3] * rl);
    *(u32x2*)(Oo + obase + dt * 16 + lg * 4) = pk;
  }
}

// ---------------- host launcher ----------------
extern "C" void kernel_launch(void* const* d_in, const int* in_sizes, int n_in,
                              void* d_out, int out_size, void* d_ws, size_t ws_size,
                              hipStream_t stream) {
  const float* x  = (const float*)d_in[0];
  const float* Wq = (const float*)d_in[1];
  const float* bq = (const float*)d_in[2];
  const float* Wk = (const float*)d_in[3];
  const float* bk = (const float*)d_in[4];
  const float* Wv = (const float*)d_in[5];
  const float* bv = (const float*)d_in[6];
  const float* Wo = (const float*)d_in[7];
  const float* bo = (const float*)d_in[8];

  char* ws = (char*)d_ws;
  u16* xb    = (u16*)(ws);                 // 8 MB  [4096,1024] bf16
  u16* wb    = (u16*)(ws + (8u << 20));    // 8 MB  Wq,Wk,Wv,Wo bf16
  u16* Qb    = (u16*)(ws + (16u << 20));   // 8 MB  [B,H,S,Dh]
  u16* Kb    = (u16*)(ws + (24u << 20));   // 8 MB  [B,H,S,Dh]
  u16* Vtb   = (u16*)(ws + (32u << 20));   // 8 MB  [B,H,Dh,S] (s-permuted)
  u16* AOb   = (u16*)(ws + (40u << 20));   // 8 MB  [B*S, DM]
  float2* rt = (float2*)(ws + (48u << 20)); // 512 KB rope table

  convert_k<<<8192, 256, 0, stream>>>(x, Wq, Wk, Wv, Wo, xb, wb);
  rope_k<<<256, 256, 0, stream>>>(rt);
  gemm_k<<<768, 256, 0, stream>>>(xb, wb, wb + (1u << 20), wb + (2u << 20),
                                  bq, bk, bv, rt, Qb, Kb, Vtb, 0);
  attn_k<<<2048, 128, 0, stream>>>(Qb, Kb, Vtb, AOb);
  gemm_k<<<256, 256, 0, stream>>>(AOb, wb + (3u << 20), wb + (3u << 20), wb + (3u << 20),
                                  bo, bo, bo, rt, d_out, d_out, d_out, 3);
}

// Round 6
// 168.499 us; speedup vs baseline: 1.6886x; 1.3220x over previous
//
#include <hip/hip_runtime.h>
#include <stdint.h>

#define S_LEN 2048
#define BATCH 2
#define DM 1024
#define NH 16
#define DH 64
#define MROWS 4096  // BATCH * S_LEN

typedef unsigned short u16;
typedef unsigned int u32;
typedef __attribute__((ext_vector_type(8))) short bf16x8;
typedef __attribute__((ext_vector_type(4))) short bf16x4;
typedef __attribute__((ext_vector_type(4))) float f32x4;
typedef __attribute__((ext_vector_type(2))) unsigned u32x2;

union pack8 { u32 w[4]; bf16x8 v8; };

__device__ inline u16 f2bf(float f) {
  union { float f; unsigned u; } v; v.f = f;
  unsigned u = v.u;
  unsigned r = u + 0x7fffu + ((u >> 16) & 1u);
  return (u16)(r >> 16);
}

__device__ inline u32 pkbf(float lo, float hi) {
  u32 r;
  asm("v_cvt_pk_bf16_f32 %0, %1, %2" : "=v"(r) : "v"(lo), "v"(hi));
  return r;
}

// ---------------- fp32 -> bf16 conversion for x, Wq, Wk, Wv, Wo ----------------
__global__ void convert_k(const float* __restrict__ x, const float* __restrict__ wq,
                          const float* __restrict__ wk, const float* __restrict__ wv,
                          const float* __restrict__ wo, u16* __restrict__ xb,
                          u16* __restrict__ wb) {
  int i = blockIdx.x * blockDim.x + threadIdx.x;
  const int total = (MROWS * DM + 4 * DM * DM) / 4;  // 2,097,152 float4 groups
  if (i >= total) return;
  int e = i * 4;
  const float* src;
  u16* dst;
  if (e < MROWS * DM) {
    src = x + e; dst = xb + e;
  } else {
    int j = e - MROWS * DM;
    int w = j >> 20;
    int o = j & ((1 << 20) - 1);
    src = (w == 0) ? wq + o : (w == 1) ? wk + o : (w == 2) ? wv + o : wo + o;
    dst = wb + j;
  }
  float4 v = *(const float4*)src;
  uint2 r;
  r.x = (unsigned)f2bf(v.x) | ((unsigned)f2bf(v.y) << 16);
  r.y = (unsigned)f2bf(v.z) | ((unsigned)f2bf(v.w) << 16);
  *(uint2*)dst = r;
}

// ---------------- RoPE cos/sin table [S][32] ----------------
__global__ void rope_k(float2* __restrict__ tab) {
  int i = blockIdx.x * blockDim.x + threadIdx.x;
  if (i >= S_LEN * 32) return;
  int s = i >> 5, p = i & 31;
  float inv = expf(-(float)p * 0.28782313662425575f);  // ln(10000)/32
  float a = (float)s * inv;
  tab[i] = make_float2(cosf(a), sinf(a));
}

// ---------------- GEMM: C = A @ W^T + bias, fused epilogues ----------------
// mode 0: Q  -> rope, *0.125*log2e, bf16 [B,H,S,Dh]   (log2e folded so attn uses exp2)
// mode 1: K  -> rope, bf16 [B,H,S,Dh]
// mode 2: V  -> bf16 [B,H,Dh,S] with per-32 s-block permutation matching the
//               attn PV fragment (pos = ((j&15)>>2)*8 + (j>>4)*4 + (j&3))
// mode 3: O  -> fp32 [M, DM]
__launch_bounds__(256)
__global__ void gemm_k(const u16* __restrict__ A,
                       const u16* __restrict__ w0, const u16* __restrict__ w1,
                       const u16* __restrict__ w2,
                       const float* __restrict__ b0, const float* __restrict__ b1,
                       const float* __restrict__ b2,
                       const float2* __restrict__ rope,
                       void* __restrict__ o0, void* __restrict__ o1, void* __restrict__ o2,
                       int mode0) {
  const int mode = mode0 + (int)(blockIdx.x >> 8);
  const int tile = blockIdx.x & 255;
  const int mt = tile >> 3, nt = tile & 7;
  const int mbase = mt * 128, nbase = nt * 128;
  const u16* W = (mode == 1) ? w1 : (mode == 2) ? w2 : w0;
  const float* bias = (mode == 1) ? b1 : (mode == 2) ? b2 : b0;
  void* outp = (mode == 1) ? o1 : (mode == 2) ? o2 : o0;

  __shared__ u16 As[128 * 40];  // padded row stride 40 (2-way bank aliasing = free)
  __shared__ u16 Bs[128 * 40];

  const int t = threadIdx.x;
  const int lane = t & 63, wvi = t >> 6;
  const int lr = lane & 15, lg = lane >> 4;
  const int wm = (wvi >> 1) * 64, wn = (wvi & 1) * 64;

  f32x4 acc[4][4] = {};
  const int srow = t >> 2;        // 0..63
  const int scol = (t & 3) * 8;   // 0,8,16,24

  for (int kk = 0; kk < DM; kk += 32) {
    bf16x8 a0 = *(const bf16x8*)(A + (size_t)(mbase + srow) * DM + kk + scol);
    bf16x8 a1 = *(const bf16x8*)(A + (size_t)(mbase + 64 + srow) * DM + kk + scol);
    bf16x8 g0 = *(const bf16x8*)(W + (size_t)(nbase + srow) * DM + kk + scol);
    bf16x8 g1 = *(const bf16x8*)(W + (size_t)(nbase + 64 + srow) * DM + kk + scol);
    __syncthreads();
    *(bf16x8*)&As[srow * 40 + scol] = a0;
    *(bf16x8*)&As[(64 + srow) * 40 + scol] = a1;
    *(bf16x8*)&Bs[srow * 40 + scol] = g0;
    *(bf16x8*)&Bs[(64 + srow) * 40 + scol] = g1;
    __syncthreads();
    bf16x8 af[4], bfr[4];
#pragma unroll
    for (int mi = 0; mi < 4; mi++)
      af[mi] = *(const bf16x8*)&As[(wm + mi * 16 + lr) * 40 + lg * 8];
#pragma unroll
    for (int ni = 0; ni < 4; ni++)
      bfr[ni] = *(const bf16x8*)&Bs[(wn + ni * 16 + lr) * 40 + lg * 8];
#pragma unroll
    for (int mi = 0; mi < 4; mi++)
#pragma unroll
      for (int ni = 0; ni < 4; ni++)
        acc[mi][ni] = __builtin_amdgcn_mfma_f32_16x16x32_bf16(af[mi], bfr[ni], acc[mi][ni], 0, 0, 0);
  }

#pragma unroll
  for (int ni = 0; ni < 4; ni++) {
    const int col = nbase + wn + ni * 16 + lr;
    const float bv = bias[col];
#pragma unroll
    for (int mi = 0; mi < 4; mi++) {
      const int row0 = mbase + wm + mi * 16 + lg * 4;
      f32x4 v = acc[mi][ni];
#pragma unroll
      for (int r = 0; r < 4; r++) {
        float val = v[r] + bv;
        const int row = row0 + r;
        if (mode <= 1) {
          float nb = __shfl_xor(val, 1);
          const int d = col & 63, p = d >> 1, s = row & (S_LEN - 1);
          float2 cs = rope[s * 32 + p];
          float ov = (d & 1) ? (nb * cs.y + val * cs.x) : (val * cs.x - nb * cs.y);
          if (mode == 0) ov *= 0.18033688011112042f;  // 1/sqrt(Dh) * log2(e)
          const int b = row >> 11, h = col >> 6;
          ((u16*)outp)[((size_t)(b * NH + h) * S_LEN + s) * DH + d] = f2bf(ov);
        } else if (mode == 2) {
          const int b = row >> 11, h = col >> 6, d = col & 63, s = row & (S_LEN - 1);
          const int j = s & 31;
          const int pos = (s & ~31) + (((j & 15) >> 2) << 3) + ((j >> 4) << 2) + (j & 3);
          ((u16*)outp)[((size_t)(b * NH + h) * DH + d) * S_LEN + pos] = f2bf(val);
        } else {
          ((float*)outp)[(size_t)row * DM + col] = val;
        }
      }
    }
  }
}

// ---- softmax + PV for one q-group (a[8] pre-masked scores; o slots stride 2) ----
__device__ __forceinline__ void sm_pv(const float a[8], float& m, float& l,
                                      bf16x8 v0, bf16x8 v1, bf16x8 v2, bf16x8 v3,
                                      f32x4* o) {
  float mx = fmaxf(fmaxf(fmaxf(a[0], a[1]), fmaxf(a[2], a[3])),
                   fmaxf(fmaxf(a[4], a[5]), fmaxf(a[6], a[7])));
  mx = fmaxf(mx, __shfl_xor(mx, 16));
  mx = fmaxf(mx, __shfl_xor(mx, 32));
  const float mn = fmaxf(m, mx);
  const float c = __builtin_amdgcn_exp2f(m - mn);  // first step: exp2(-inf)=0
  m = mn;
  float p[8];
#pragma unroll
  for (int r = 0; r < 8; r++) p[r] = __builtin_amdgcn_exp2f(a[r] - mn);
  l = l * c + (((p[0] + p[1]) + (p[2] + p[3])) + ((p[4] + p[5]) + (p[6] + p[7])));
  pack8 pu;
  pu.w[0] = pkbf(p[0], p[1]);
  pu.w[1] = pkbf(p[2], p[3]);
  pu.w[2] = pkbf(p[4], p[5]);
  pu.w[3] = pkbf(p[6], p[7]);
#pragma unroll
  for (int i = 0; i < 4; i++)
#pragma unroll
    for (int r = 0; r < 4; r++) o[i * 2][r] *= c;
  o[0] = __builtin_amdgcn_mfma_f32_16x16x32_bf16(v0, pu.v8, o[0], 0, 0, 0);
  o[2] = __builtin_amdgcn_mfma_f32_16x16x32_bf16(v1, pu.v8, o[2], 0, 0, 0);
  o[4] = __builtin_amdgcn_mfma_f32_16x16x32_bf16(v2, pu.v8, o[4], 0, 0, 0);
  o[6] = __builtin_amdgcn_mfma_f32_16x16x32_bf16(v3, pu.v8, o[6], 0, 0, 0);
}

// ---------------- causal flash attention: QBLK=32 per wave, full kv range ----------------
// Two q-groups (A: rows qbase..+15, B: +16..+31) share every K/V fragment ->
// 2x arithmetic intensity, two independent softmax chains (ILP). No kv-split,
// no LDS, no inter-wave merge (R5's merge machinery removed for bisection).
// Each of the block's 2 waves owns its own q-tile, issued longest-first.
__launch_bounds__(128)
__global__ void attn_k(const u16* __restrict__ Q, const u16* __restrict__ K,
                       const u16* __restrict__ Vt, u16* __restrict__ Oo) {
  const int bh = blockIdx.x & 31;
  const int pr = blockIdx.x >> 5;           // 0..31
  const int wv = threadIdx.x >> 6;          // wave 0/1
  const int lane = threadIdx.x & 63;
  const int lr = lane & 15, lg = lane >> 4;
  const int tile = 63 - (pr * 2 + wv);      // longest first (causal load balance)
  const int qbase = tile * 32;

  const size_t qoff = ((size_t)bh * S_LEN + qbase + lr) * DH + lg * 8;
  const bf16x8 qA0 = *(const bf16x8*)(Q + qoff);
  const bf16x8 qA1 = *(const bf16x8*)(Q + qoff + 32);
  const bf16x8 qB0 = *(const bf16x8*)(Q + qoff + 16 * DH);
  const bf16x8 qB1 = *(const bf16x8*)(Q + qoff + 16 * DH + 32);

  f32x4 o[8] = {};                          // [dt][qg] -> o[dt*2+qg]
  float mA = -__builtin_inff(), mB = -__builtin_inff(), lA = 0.f, lB = 0.f;
  const f32x4 zero = {};
  const int nst = tile + 1;                 // 32-wide kv steps; last one masked

  const u16* Kp = K + ((size_t)bh * S_LEN + lr) * DH + lg * 8;
  const u16* Vp = Vt + ((size_t)bh * DH + lr) * S_LEN + lg * 8;
  bf16x8 kc0 = *(const bf16x8*)(Kp);
  bf16x8 kc1 = *(const bf16x8*)(Kp + 32);
  bf16x8 kc2 = *(const bf16x8*)(Kp + 16 * DH);
  bf16x8 kc3 = *(const bf16x8*)(Kp + 16 * DH + 32);

  // ---- hot loop: unmasked steps 0 .. nst-2, branch-free single BB ----
  for (int it = 0; it < nst - 1; ++it) {
    bf16x8 v0 = *(const bf16x8*)(Vp);
    bf16x8 v1 = *(const bf16x8*)(Vp + 16 * S_LEN);
    bf16x8 v2 = *(const bf16x8*)(Vp + 32 * S_LEN);
    bf16x8 v3 = *(const bf16x8*)(Vp + 48 * S_LEN);
    Vp += 32;

    f32x4 sA0 = __builtin_amdgcn_mfma_f32_16x16x32_bf16(kc0, qA0, zero, 0, 0, 0);
    sA0 = __builtin_amdgcn_mfma_f32_16x16x32_bf16(kc1, qA1, sA0, 0, 0, 0);
    f32x4 sA1 = __builtin_amdgcn_mfma_f32_16x16x32_bf16(kc2, qA0, zero, 0, 0, 0);
    sA1 = __builtin_amdgcn_mfma_f32_16x16x32_bf16(kc3, qA1, sA1, 0, 0, 0);
    f32x4 sB0 = __builtin_amdgcn_mfma_f32_16x16x32_bf16(kc0, qB0, zero, 0, 0, 0);
    sB0 = __builtin_amdgcn_mfma_f32_16x16x32_bf16(kc1, qB1, sB0, 0, 0, 0);
    f32x4 sB1 = __builtin_amdgcn_mfma_f32_16x16x32_bf16(kc2, qB0, zero, 0, 0, 0);
    sB1 = __builtin_amdgcn_mfma_f32_16x16x32_bf16(kc3, qB1, sB1, 0, 0, 0);

    // prefetch next step's K (last prefetch = the masked step's tile, in-bounds)
    Kp += 32 * DH;
    kc0 = *(const bf16x8*)(Kp);
    kc1 = *(const bf16x8*)(Kp + 32);
    kc2 = *(const bf16x8*)(Kp + 16 * DH);
    kc3 = *(const bf16x8*)(Kp + 16 * DH + 32);

    float aA[8], aB[8];
#pragma unroll
    for (int r = 0; r < 4; r++) {
      aA[r] = sA0[r]; aA[4 + r] = sA1[r];
      aB[r] = sB0[r]; aB[4 + r] = sB1[r];
    }
    sm_pv(aA, mA, lA, v0, v1, v2, v3, &o[0]);
    sm_pv(aB, mB, lB, v0, v1, v2, v3, &o[1]);
  }

  // ---- peeled masked diagonal step (kv = qbase), straight-line ----
  {
    bf16x8 v0 = *(const bf16x8*)(Vp);
    bf16x8 v1 = *(const bf16x8*)(Vp + 16 * S_LEN);
    bf16x8 v2 = *(const bf16x8*)(Vp + 32 * S_LEN);
    bf16x8 v3 = *(const bf16x8*)(Vp + 48 * S_LEN);

    f32x4 sA0 = __builtin_amdgcn_mfma_f32_16x16x32_bf16(kc0, qA0, zero, 0, 0, 0);
    sA0 = __builtin_amdgcn_mfma_f32_16x16x32_bf16(kc1, qA1, sA0, 0, 0, 0);
    f32x4 sA1 = __builtin_amdgcn_mfma_f32_16x16x32_bf16(kc2, qA0, zero, 0, 0, 0);
    sA1 = __builtin_amdgcn_mfma_f32_16x16x32_bf16(kc3, qA1, sA1, 0, 0, 0);
    f32x4 sB0 = __builtin_amdgcn_mfma_f32_16x16x32_bf16(kc0, qB0, zero, 0, 0, 0);
    sB0 = __builtin_amdgcn_mfma_f32_16x16x32_bf16(kc1, qB1, sB0, 0, 0, 0);
    f32x4 sB1 = __builtin_amdgcn_mfma_f32_16x16x32_bf16(kc2, qB0, zero, 0, 0, 0);
    sB1 = __builtin_amdgcn_mfma_f32_16x16x32_bf16(kc3, qB1, sB1, 0, 0, 0);

    // A group: q = qbase+lr; kv rows qbase+lg*4+r (s0), qbase+16+lg*4+r (s1, all masked)
    const int qrelA = lr - lg * 4;
    // B group: q = qbase+16+lr; s0 all valid; s1 masked by r+16 <= qrelB
    const int qrelB = qrelA + 16;
    float aA[8], aB[8];
#pragma unroll
    for (int r = 0; r < 4; r++) {
      aA[r]     = (r <= qrelA)      ? sA0[r] : -__builtin_inff();
      aA[4 + r] = (r + 16 <= qrelA) ? sA1[r] : -__builtin_inff();
      aB[r]     = sB0[r];
      aB[4 + r] = (r + 16 <= qrelB) ? sB1[r] : -__builtin_inff();
    }
    sm_pv(aA, mA, lA, v0, v1, v2, v3, &o[0]);
    sm_pv(aB, mB, lB, v0, v1, v2, v3, &o[1]);
  }

  // ---- epilogue: lane holds q=lr (col), d = dt*16 + lg*4 + r; no merge ----
  lA += __shfl_xor(lA, 16); lA += __shfl_xor(lA, 32);
  lB += __shfl_xor(lB, 16); lB += __shfl_xor(lB, 32);
  const float rlA = __builtin_amdgcn_rcpf(lA);
  const float rlB = __builtin_amdgcn_rcpf(lB);

  const int b = bh >> 4, h = bh & 15;
  const size_t obaseA = ((size_t)b * S_LEN + qbase + lr) * DM + h * DH;
  const size_t obaseB = obaseA + (size_t)16 * DM;
#pragma unroll
  for (int dt = 0; dt < 4; dt++) {
    u32x2 pkA, pkB;
    pkA.x = pkbf(o[dt * 2][0] * rlA, o[dt * 2][1] * rlA);
    pkA.y = pkbf(o[dt * 2][2] * rlA, o[dt * 2][3] * rlA);
    pkB.x = pkbf(o[dt * 2 + 1][0] * rlB, o[dt * 2 + 1][1] * rlB);
    pkB.y = pkbf(o[dt * 2 + 1][2] * rlB, o[dt * 2 + 1][3] * rlB);
    *(u32x2*)(Oo + obaseA + dt * 16 + lg * 4) = pkA;
    *(u32x2*)(Oo + obaseB + dt * 16 + lg * 4) = pkB;
  }
}

// ---------------- host launcher ----------------
extern "C" void kernel_launch(void* const* d_in, const int* in_sizes, int n_in,
                              void* d_out, int out_size, void* d_ws, size_t ws_size,
                              hipStream_t stream) {
  const float* x  = (const float*)d_in[0];
  const float* Wq = (const float*)d_in[1];
  const float* bq = (const float*)d_in[2];
  const float* Wk = (const float*)d_in[3];
  const float* bk = (const float*)d_in[4];
  const float* Wv = (const float*)d_in[5];
  const float* bv = (const float*)d_in[6];
  const float* Wo = (const float*)d_in[7];
  const float* bo = (const float*)d_in[8];

  char* ws = (char*)d_ws;
  u16* xb    = (u16*)(ws);                 // 8 MB  [4096,1024] bf16
  u16* wb    = (u16*)(ws + (8u << 20));    // 8 MB  Wq,Wk,Wv,Wo bf16
  u16* Qb    = (u16*)(ws + (16u << 20));   // 8 MB  [B,H,S,Dh]
  u16* Kb    = (u16*)(ws + (24u << 20));   // 8 MB  [B,H,S,Dh]
  u16* Vtb   = (u16*)(ws + (32u << 20));   // 8 MB  [B,H,Dh,S] (s-permuted)
  u16* AOb   = (u16*)(ws + (40u << 20));   // 8 MB  [B*S, DM]
  float2* rt = (float2*)(ws + (48u << 20)); // 512 KB rope table

  convert_k<<<8192, 256, 0, stream>>>(x, Wq, Wk, Wv, Wo, xb, wb);
  rope_k<<<256, 256, 0, stream>>>(rt);
  gemm_k<<<768, 256, 0, stream>>>(xb, wb, wb + (1u << 20), wb + (2u << 20),
                                  bq, bk, bv, rt, Qb, Kb, Vtb, 0);
  attn_k<<<1024, 128, 0, stream>>>(Qb, Kb, Vtb, AOb);
  gemm_k<<<256, 256, 0, stream>>>(AOb, wb + (3u << 20), wb + (3u << 20), wb + (3u << 20),
                                  bo, bo, bo, rt, d_out, d_out, d_out, 3);
}